// Round 9
// baseline (138.906 us; speedup 1.0000x reference)
//
#include <hip/hip_runtime.h>

typedef unsigned short u16;
typedef unsigned int   u32;
typedef _Float16 h2  __attribute__((ext_vector_type(2)));   // arithmetic type
typedef __fp16   hw2 __attribute__((ext_vector_type(2)));   // builtin boundary
typedef __fp16   hw8 __attribute__((ext_vector_type(8)));   // mfma operand
typedef float    f4  __attribute__((ext_vector_type(4)));   // mfma accumulator

// LDS row stride for sX / sXl in u16 elements: 136*2 = 272 B -> row starts 16B-aligned.
#define XS 136
#define PS 72    // sP   row stride (u16):  P[h][j][i], i contiguous (A-fragment ready)
#define BS 72    // sXlB row stride (u16):  xl^T[c][i], i contiguous (B-fragment ready)

static __device__ __forceinline__ h2 pk(float a, float b) {
    return __builtin_bit_cast(h2, __builtin_amdgcn_cvt_pkrtz(a, b));
}
static __device__ __forceinline__ float dot2(h2 a, h2 b, float c) {
    return __builtin_amdgcn_fdot2(__builtin_bit_cast(hw2, a),
                                  __builtin_bit_cast(hw2, b), c, false);   // v_dot2_f32_f16
}
static __device__ __forceinline__ h2  b2h(u32 v) { return __builtin_bit_cast(h2, v); }
static __device__ __forceinline__ u32 h2u(h2 v)  { return __builtin_bit_cast(u32, v); }
static __device__ __forceinline__ h2  abs2(h2 v) { return b2h(h2u(v) & 0x7fff7fffu); }
static __device__ __forceinline__ u16 f2h(float f) { return __builtin_bit_cast(u16, (_Float16)f); }
static __device__ __forceinline__ f4 mfma16(uint4 a, uint4 b, f4 c) {
    return __builtin_amdgcn_mfma_f32_16x16x32_f16(__builtin_bit_cast(hw8, a),
                                                  __builtin_bit_cast(hw8, b), c, 0, 0, 0);
}

// ---------------- K0: pack weights f32 -> MFMA B-fragment-ordered f16 ----------------
// wpk (u32): [0]=L1 [8192]=R1 [16384]=L2 [24576]=R2 [32768]=L3 [36864]=R3 ; 160 KB
__global__ void pack_weights(const float* __restrict__ Wl1, const float* __restrict__ Wr1,
                             const float* __restrict__ Wl2, const float* __restrict__ Wr2,
                             const float* __restrict__ Wl3, const float* __restrict__ Wr3,
                             u32* __restrict__ wpk)
{
    const int o = blockIdx.x * 256 + threadIdx.x;    // 0 .. 40959
    const float* src; u32* dst; int local; int N;
    if      (o < 8192)  { src = Wl1; dst = wpk;         local = o;         N = 128; }
    else if (o < 16384) { src = Wr1; dst = wpk + 8192;  local = o - 8192;  N = 128; }
    else if (o < 24576) { src = Wl2; dst = wpk + 16384; local = o - 16384; N = 128; }
    else if (o < 32768) { src = Wr2; dst = wpk + 24576; local = o - 24576; N = 128; }
    else if (o < 36864) { src = Wl3; dst = wpk + 32768; local = o - 32768; N = 64;  }
    else                { src = Wr3; dst = wpk + 36864; local = o - 36864; N = 64;  }
    const int i2   = local & 3;
    const int lane = (local >> 2) & 63;
    const int frag = local >> 8;
    const int kb   = frag & 3;
    const int nt   = frag >> 2;
    const int k0   = kb*32 + ((lane >> 4) << 3) + i2*2;
    const int n    = nt*16 + (lane & 15);
    dst[local] = h2u(pk(src[k0*N + n], src[(k0+1)*N + n]));
}

// ---------------- shared device pieces ----------------
static __device__ __forceinline__ void compute_imp(int t, int b,
    const float* __restrict__ team_mask, const float* __restrict__ ltm, float* sImp)
{
    if (t < 64) {
        float im;
        if (t < 16) im = (team_mask[b*32 + t] != -1000000000.0f) ? 1.f : 0.f;
        else        im = (ltm[b*49 + (t-16)] != 0.0f) ? 1.f : 0.f;
        sImp[t] = im;
    }
}

// full 128-col MFMA projection, 16 waves: mt = w&3, isR = (w>>2)&1, nt-half = w>>3.
// Writes: sXl row-major (scores), sXlB col-major (agg B-frags), sXrP packed.
static __device__ __forceinline__ void matmul128(int w, int lane,
    const u32* __restrict__ wpkL, const u32* __restrict__ wpkR,
    const u16* sX, u16* sXl, uint4* sXrP, u16* sXlB)
{
    const int  mt  = w & 3;
    const bool isR = (w >> 2) & 1;
    const int  nh  = w >> 3;
    const u32* wp  = isR ? wpkR : wpkL;
    const int  n15 = lane & 15;
    const int  qd  = lane >> 4;
    uint4 afr[4];
#pragma unroll
    for (int kb = 0; kb < 4; kb++)
        afr[kb] = *(const uint4*)&sX[(mt*16 + n15)*XS + kb*32 + (qd << 3)];
#pragma unroll
    for (int nt = nh*4; nt < nh*4 + 4; nt++) {
        f4 acc = {0.f, 0.f, 0.f, 0.f};
#pragma unroll
        for (int kb = 0; kb < 4; kb++) {
            uint4 bf = *(const uint4*)&wp[((nt*4 + kb)*64 + lane)*4];
            acc = mfma16(afr[kb], bf, acc);
        }
        const int n  = nt*16 + n15;
        const int mb = mt*16 + (qd << 2);
        if (!isR) {
#pragma unroll
            for (int r = 0; r < 4; r++) sXl[(mb + r)*XS + n] = f2h(acc[r]);
            uint2 u;
            u.x = h2u(pk(acc[0], acc[1]));
            u.y = h2u(pk(acc[2], acc[3]));
            *(uint2*)&sXlB[n*BS + mb] = u;
        } else {
            u16* xp = (u16*)sXrP;
#pragma unroll
            for (int r = 0; r < 4; r++)
                xp[(((n >> 3)*64) + mb + r)*8 + (n & 7)] = f2h(acc[r]);
        }
    }
}

// scores (H=4,C=32): thread (h = w&3, qf = w>>2, j = lane) computes p for 16 i's.
// Al self-computed per wave via shuffle broadcast (no sAl, no internal barrier).
static __device__ __forceinline__ void attn_scores(int w, int lane,
    const float* __restrict__ att,
    const u16* sXl, const uint4* sXrP, u16* sP,
    float* sL2, const float* sImp)
{
    const int h  = w & 3;
    const int qf = w >> 2;     // i-quarter 0..3
    const int j  = lane;

    h2 a2[16];
#pragma unroll
    for (int q = 0; q < 16; q++) a2[q] = pk(att[h*32 + 2*q], att[h*32 + 2*q + 1]);

    // self-computed Al for this wave's 16 i's: lane (&15) handles i = qf*16 + (lane&15)
    float al;
    {
        const int ia = qf*16 + (lane & 15);
        const uint4* pr = (const uint4*)&sXl[ia*XS + h*32];
        al = 0.f;
#pragma unroll
        for (int c4 = 0; c4 < 4; c4++) {
            uint4 v = pr[c4];
            al = dot2(b2h(v.x), a2[c4*4+0], al);
            al = dot2(b2h(v.y), a2[c4*4+1], al);
            al = dot2(b2h(v.z), a2[c4*4+2], al);
            al = dot2(b2h(v.w), a2[c4*4+3], al);
        }
    }

    h2 xr2[16];
#pragma unroll
    for (int s = 0; s < 4; s++) {
        uint4 v = sXrP[(h*4 + s)*64 + j];
        xr2[s*4+0] = b2h(v.x); xr2[s*4+1] = b2h(v.y);
        xr2[s*4+2] = b2h(v.z); xr2[s*4+3] = b2h(v.w);
    }
    float Ar = 0.f;
#pragma unroll
    for (int q = 0; q < 16; q++) Ar = dot2(a2[q], xr2[q], Ar);
    const float impj = sImp[j];

    float l = 0.f;
    uint4* pd = (uint4*)&sP[(h*64 + j)*PS + qf*16];
    for (int c8 = 0; c8 < 2; c8++) {          // rolled outer; all reg indices static inside
        u32 pr4[4];
        float pprev = 0.f;
#pragma unroll
        for (int i2 = 0; i2 < 8; i2++) {
            const int idx = c8*8 + i2;
            const int i   = qf*16 + idx;
            const uint4* pl = (const uint4*)&sXl[i*XS + h*32];
            uint4 v0 = pl[0], v1 = pl[1], v2 = pl[2], v3 = pl[3];
            h2 xl2[16];
            xl2[0] = b2h(v0.x); xl2[1] = b2h(v0.y); xl2[2]  = b2h(v0.z); xl2[3]  = b2h(v0.w);
            xl2[4] = b2h(v1.x); xl2[5] = b2h(v1.y); xl2[6]  = b2h(v1.z); xl2[7]  = b2h(v1.w);
            xl2[8] = b2h(v2.x); xl2[9] = b2h(v2.y); xl2[10] = b2h(v2.z); xl2[11] = b2h(v2.w);
            xl2[12]= b2h(v3.x); xl2[13]= b2h(v3.y); xl2[14] = b2h(v3.z); xl2[15] = b2h(v3.w);
            float S0 = 0.f, S1 = 0.f;
#pragma unroll
            for (int q = 0; q < 16; q += 2) {
                h2 t0 = abs2(xl2[q]   + xr2[q]);
                h2 t1 = abs2(xl2[q+1] + xr2[q+1]);
                S0 = dot2(a2[q],   t0, S0);
                S1 = dot2(a2[q+1], t1, S1);
            }
            const float Al_i = __shfl(al, idx);
            float e  = 0.6f*(Al_i + Ar) + 0.4f*(S0 + S1);
            float ad = (i == j) ? 1.f : impj * sImp[i];
            float p  = (ad != 0.f) ? __expf(e) : 0.f;
            if (i2 & 1) {
                h2 pp = pk(pprev, p);
                pr4[i2 >> 1] = h2u(pp);
                l += (float)pp[0] + (float)pp[1];   // denom from f16-rounded p (matches MFMA)
            } else {
                pprev = p;
            }
        }
        pd[c8] = make_uint4(pr4[0], pr4[1], pr4[2], pr4[3]);
    }
    sL2[h*256 + qf*64 + j] = l;
}

// MFMA aggregation + bias + LN + ReLU, all in registers; cross-lane LN partials via
// shfl_xor over the 16 n15-lanes (the c dimension); one barrier; writes f16 to sXout.
// 16 waves: h = w&3, jq = w>>2 (16-j tile each).
static __device__ __forceinline__ void attn_agg_ln(int w, int lane,
    const float* __restrict__ bias, const float* __restrict__ lg, const float* __restrict__ lb,
    const u16* sP, const u16* sXlB, const float* sL2,
    float* sPart, u16* sXout)
{
    const int h   = w & 3;
    const int jq  = w >> 2;
    const int n15 = lane & 15;
    const int kq  = lane >> 4;

    f4 acc0 = {0.f,0.f,0.f,0.f}, acc1 = acc0;
#pragma unroll
    for (int ks = 0; ks < 2; ks++) {
        uint4 af  = *(const uint4*)&sP[(h*64 + jq*16 + n15)*PS + ks*32 + kq*8];
        uint4 bf0 = *(const uint4*)&sXlB[(h*32 +  0 + n15)*BS + ks*32 + kq*8];
        uint4 bf1 = *(const uint4*)&sXlB[(h*32 + 16 + n15)*BS + ks*32 + kq*8];
        acc0 = mfma16(af, bf0, acc0);
        acc1 = mfma16(af, bf1, acc1);
    }
    // lane holds: c0 = h*32+n15 (acc0), c1 = c0+16 (acc1); j = jq*16 + kq*4 + r
    const int c0 = h*32 + n15, c1 = c0 + 16;
    const float bc0 = bias[c0], bc1 = bias[c1];
    float y0[4], y1[4], s1v[4], s2v[4];
#pragma unroll
    for (int r = 0; r < 4; r++) {
        const int jr = jq*16 + kq*4 + r;
        const float lr = (sL2[h*256 + jr]       + sL2[h*256 +  64 + jr])
                       + (sL2[h*256 + 128 + jr] + sL2[h*256 + 192 + jr]);
        const float rl = 1.f / lr;
        y0[r] = fmaf(acc0[r], rl, bc0);
        y1[r] = fmaf(acc1[r], rl, bc1);
        s1v[r] = y0[r] + y1[r];
        s2v[r] = fmaf(y0[r], y0[r], y1[r]*y1[r]);
    }
    // reduce Σy, Σy² across the 16 n15-lanes (c within this head's 32 channels)
#pragma unroll
    for (int off = 1; off < 16; off <<= 1) {
#pragma unroll
        for (int r = 0; r < 4; r++) {
            s1v[r] += __shfl_xor(s1v[r], off);
            s2v[r] += __shfl_xor(s2v[r], off);
        }
    }
    if (n15 == 0) {
#pragma unroll
        for (int r = 0; r < 4; r++) {
            const int jr = jq*16 + kq*4 + r;
            sPart[jr*8 + h]     = s1v[r];
            sPart[jr*8 + 4 + h] = s2v[r];
        }
    }
    __syncthreads();   // per-(j,h) partials ready

    const float g0 = lg[c0], g1 = lg[c1], e0 = lb[c0], e1 = lb[c1];
#pragma unroll
    for (int r = 0; r < 4; r++) {
        const int jr = jq*16 + kq*4 + r;
        const float4 sv1 = *(const float4*)&sPart[jr*8];
        const float4 sv2 = *(const float4*)&sPart[jr*8 + 4];
        const float su = (sv1.x + sv1.y) + (sv1.z + sv1.w);
        const float sq = (sv2.x + sv2.y) + (sv2.z + sv2.w);
        const float mean = su * 0.0078125f;
        const float var  = sq * 0.0078125f - mean*mean;
        const float rstd = rsqrtf(var + 1e-5f);
        float v0 = fmaxf(fmaf((y0[r] - mean)*rstd, g0, e0), 0.f);
        float v1 = fmaxf(fmaf((y1[r] - mean)*rstd, g1, e1), 0.f);
        sXout[jr*XS + c0] = f2h(v0);
        sXout[jr*XS + c1] = f2h(v1);
    }
}

// ---------------- fused kernel: embed + GAT1 + GAT2 + GAT3, one block per batch ----------------
__global__ void __launch_bounds__(1024, 4) gnn_fused(
    const float* __restrict__ team_obs, const float* __restrict__ target_obs,
    const float* __restrict__ team_mask, const float* __restrict__ ltm,
    const float* __restrict__ W_emb, const float* __restrict__ b_emb,
    const float* __restrict__ att1, const float* __restrict__ b1,
    const float* __restrict__ ln1_g, const float* __restrict__ ln1_b,
    const float* __restrict__ att2, const float* __restrict__ b2,
    const float* __restrict__ ln2_g, const float* __restrict__ ln2_b,
    const float* __restrict__ att3, const float* __restrict__ b3,
    const u32* __restrict__ wpk, float* __restrict__ out)
{
    __shared__ __align__(16) u16   sX  [64*XS];    // activations (layer input)
    __shared__ __align__(16) u16   sXl [64*XS];    // xl projection, row-major
    __shared__ __align__(16) uint4 sXrP[1024];     // xr projection, packed per node
    __shared__ __align__(16) u16   sXlB[128*BS];   // xl^T col-major (MFMA B-frags)
    __shared__ __align__(16) u16   sP  [4*64*PS];  // P[h][j][i] f16 (MFMA A-frags); sFin overlay
    __shared__ float sPart[1024];
    __shared__ float sL2 [1024];
    __shared__ float sImp[64];

    const int t    = threadIdx.x;
    const int w    = t >> 6;
    const int lane = t & 63;
    const int b    = blockIdx.x;                   // one batch per block

    float* sFin = (float*)sP;                      // 4 KB overlay, embed phase only

    compute_imp(t, b, team_mask, ltm, sImp);
    {
        int m = t >> 4, k = t & 15;                // 1024 threads -> all 64x16 elements
        float v = 0.f;
        if (m < 16) {
            if (k < 14) v = team_obs[(b*16 + m)*14 + k];
        } else {
            const float* tg = target_obs + (size_t)(b*48 + (m-16))*15;
            if      (k < 12)  v = tg[k];
            else if (k == 14) v = tg[12];
            else if (k == 15) v = tg[13];
        }
        sFin[m*16 + k] = v;
    }
    __syncthreads();

    // embed: x = fin @ W_emb + b_emb -> sX (f16); 8 groups x 8 rows
    {
        const int f = t & 127;
        const int g = t >> 7;
        float wreg[16];
#pragma unroll
        for (int k = 0; k < 16; k++) wreg[k] = W_emb[k*128 + f];
        const float bf = b_emb[f];
#pragma unroll
        for (int mm = 0; mm < 8; mm++) {
            int m = g*8 + mm;
            const float4* pf = (const float4*)&sFin[m*16];
            float4 f0 = pf[0], f1 = pf[1], f2 = pf[2], f3 = pf[3];
            float acc = bf;
            acc = fmaf(f0.x, wreg[0],  acc); acc = fmaf(f0.y, wreg[1],  acc);
            acc = fmaf(f0.z, wreg[2],  acc); acc = fmaf(f0.w, wreg[3],  acc);
            acc = fmaf(f1.x, wreg[4],  acc); acc = fmaf(f1.y, wreg[5],  acc);
            acc = fmaf(f1.z, wreg[6],  acc); acc = fmaf(f1.w, wreg[7],  acc);
            acc = fmaf(f2.x, wreg[8],  acc); acc = fmaf(f2.y, wreg[9],  acc);
            acc = fmaf(f2.z, wreg[10], acc); acc = fmaf(f2.w, wreg[11], acc);
            acc = fmaf(f3.x, wreg[12], acc); acc = fmaf(f3.y, wreg[13], acc);
            acc = fmaf(f3.z, wreg[14], acc); acc = fmaf(f3.w, wreg[15], acc);
            sX[m*XS + f] = f2h(acc);
        }
    }
    __syncthreads();

    // -------- layer 1 --------
    matmul128(w, lane, wpk, wpk + 8192, sX, sXl, sXrP, sXlB);
    __syncthreads();
    attn_scores(w, lane, att1, sXl, sXrP, sP, sL2, sImp);
    __syncthreads();
    attn_agg_ln(w, lane, b1, ln1_g, ln1_b, sP, sXlB, sL2, sPart, sX);
    __syncthreads();

    // -------- layer 2 --------
    matmul128(w, lane, wpk + 16384, wpk + 24576, sX, sXl, sXrP, sXlB);
    __syncthreads();
    attn_scores(w, lane, att2, sXl, sXrP, sP, sL2, sImp);
    __syncthreads();
    attn_agg_ln(w, lane, b2, ln2_g, ln2_b, sP, sXlB, sL2, sPart, sX);
    __syncthreads();

    // -------- layer 3 (H=1, C=64) --------
    {
        const int  mt  = w & 3;
        const bool isR = (w >> 2) & 1;
        const int  nh  = w >> 3;
        const u32* wp  = isR ? (wpk + 36864) : (wpk + 32768);
        const int  n15 = lane & 15;
        const int  qd  = lane >> 4;
        uint4 afr[4];
#pragma unroll
        for (int kb = 0; kb < 4; kb++)
            afr[kb] = *(const uint4*)&sX[(mt*16 + n15)*XS + kb*32 + (qd << 3)];
#pragma unroll
        for (int nt = nh*2; nt < nh*2 + 2; nt++) {
            f4 acc = {0.f, 0.f, 0.f, 0.f};
#pragma unroll
            for (int kb = 0; kb < 4; kb++) {
                uint4 bf = *(const uint4*)&wp[((nt*4 + kb)*64 + lane)*4];
                acc = mfma16(afr[kb], bf, acc);
            }
            const int n  = nt*16 + n15;
            const int mb = mt*16 + (qd << 2);
            if (!isR) {
#pragma unroll
                for (int r = 0; r < 4; r++) sXl[(mb + r)*XS + n] = f2h(acc[r]);
                uint2 u;
                u.x = h2u(pk(acc[0], acc[1]));
                u.y = h2u(pk(acc[2], acc[3]));
                *(uint2*)&sXlB[n*BS + mb] = u;
            } else {
                u16* xp = (u16*)sXrP;
#pragma unroll
                for (int r = 0; r < 4; r++)
                    xp[(((n >> 3)*64) + mb + r)*8 + (n & 7)] = f2h(acc[r]);
            }
        }
    }
    __syncthreads();

    // scores3: thread (w, j=lane) handles 4 i's; Al3 self-computed via shuffle.
    {
        h2 a3[32], xr3[32];
#pragma unroll
        for (int q = 0; q < 32; q++) a3[q] = pk(att3[2*q], att3[2*q + 1]);
        // self Al3: lane (&3) computes i = w*4 + (lane&3), full 64 channels
        float al3;
        {
            const int ia = w*4 + (lane & 3);
            const uint4* pl = (const uint4*)&sXl[ia*XS];
            al3 = 0.f;
#pragma unroll
            for (int c4 = 0; c4 < 8; c4++) {
                uint4 v = pl[c4];
                al3 = dot2(b2h(v.x), a3[c4*4+0], al3);
                al3 = dot2(b2h(v.y), a3[c4*4+1], al3);
                al3 = dot2(b2h(v.z), a3[c4*4+2], al3);
                al3 = dot2(b2h(v.w), a3[c4*4+3], al3);
            }
        }
#pragma unroll
        for (int s = 0; s < 8; s++) {
            uint4 v = sXrP[s*64 + lane];
            xr3[s*4+0] = b2h(v.x); xr3[s*4+1] = b2h(v.y);
            xr3[s*4+2] = b2h(v.z); xr3[s*4+3] = b2h(v.w);
        }
        float Ar = 0.f;
#pragma unroll
        for (int q = 0; q < 32; q++) Ar = dot2(a3[q], xr3[q], Ar);
        const float impj = sImp[lane];
        float l3 = 0.f;
        u32 pr2[2];
        float pprev = 0.f;
#pragma unroll
        for (int ii = 0; ii < 4; ii++) {
            const int i = w*4 + ii;
            const uint4* pl = (const uint4*)&sXl[i*XS];
            float S0 = 0.f, S1 = 0.f;
#pragma unroll
            for (int c4 = 0; c4 < 8; c4++) {
                uint4 v = pl[c4];
                S0 = dot2(a3[c4*4+0], abs2(b2h(v.x) + xr3[c4*4+0]), S0);
                S1 = dot2(a3[c4*4+1], abs2(b2h(v.y) + xr3[c4*4+1]), S1);
                S0 = dot2(a3[c4*4+2], abs2(b2h(v.z) + xr3[c4*4+2]), S0);
                S1 = dot2(a3[c4*4+3], abs2(b2h(v.w) + xr3[c4*4+3]), S1);
            }
            const float Al_i = __shfl(al3, ii);
            float e  = 0.6f*(Al_i + Ar) + 0.4f*(S0 + S1);
            float ad = (i == lane) ? 1.f : impj * sImp[i];
            float p  = (ad != 0.f) ? __expf(e) : 0.f;
            if (ii & 1) {
                h2 pp = pk(pprev, p);
                pr2[ii >> 1] = h2u(pp);
                l3 += (float)pp[0] + (float)pp[1];
            } else {
                pprev = p;
            }
        }
        *(uint2*)&sP[lane*PS + w*4] = make_uint2(pr2[0], pr2[1]);
        sPart[w*64 + lane] = l3;
    }
    __syncthreads();
    if (t < 64) {
        float s = 0.f;
#pragma unroll
        for (int p = 0; p < 16; p += 4)
            s += ((sPart[p*64 + t] + sPart[(p+1)*64 + t]) +
                  (sPart[(p+2)*64 + t] + sPart[(p+3)*64 + t]));
        sL2[t] = 1.f / s;
    }

    // agg3 via MFMA: out[j,c] = sum_i P3[i,j]*xl3[i,c]; 16 waves: jt = w&3, ct = w>>2
    {
        const int jt  = w & 3;
        const int ct  = w >> 2;
        const int n15 = lane & 15;
        const int kq  = lane >> 4;
        f4 acc = {0.f,0.f,0.f,0.f};
#pragma unroll
        for (int ks = 0; ks < 2; ks++) {
            uint4 af = *(const uint4*)&sP[(jt*16 + n15)*PS + ks*32 + kq*8];
            uint4 bf = *(const uint4*)&sXlB[(ct*16 + n15)*BS + ks*32 + kq*8];
            acc = mfma16(af, bf, acc);
        }
        __syncthreads();   // sL2 (1/l) ready
        const int c  = ct*16 + n15;
        const float bc = b3[c];
#pragma unroll
        for (int r = 0; r < 4; r++) {
            const int jj = jt*16 + kq*4 + r;
            out[(size_t)b*4096 + (size_t)jj*64 + c] = fmaf(acc[r], sL2[jj], bc);
        }
    }
}

extern "C" void kernel_launch(void* const* d_in, const int* in_sizes, int n_in,
                              void* d_out, int out_size, void* d_ws, size_t ws_size,
                              hipStream_t stream) {
    (void)in_sizes; (void)n_in; (void)ws_size; (void)out_size;
    const float* team_obs          = (const float*)d_in[0];
    const float* target_obs        = (const float*)d_in[1];
    const float* team_mask         = (const float*)d_in[2];
    const float* local_target_mask = (const float*)d_in[3];
    const float* W_emb             = (const float*)d_in[4];
    const float* b_emb             = (const float*)d_in[5];
    const float* Wl1               = (const float*)d_in[6];
    const float* Wr1               = (const float*)d_in[7];
    const float* att1              = (const float*)d_in[8];
    const float* b1                = (const float*)d_in[9];
    const float* Wl2               = (const float*)d_in[10];
    const float* Wr2               = (const float*)d_in[11];
    const float* att2              = (const float*)d_in[12];
    const float* b2                = (const float*)d_in[13];
    const float* Wl3               = (const float*)d_in[14];
    const float* Wr3               = (const float*)d_in[15];
    const float* att3              = (const float*)d_in[16];
    const float* b3                = (const float*)d_in[17];
    const float* ln1_g             = (const float*)d_in[18];
    const float* ln1_b             = (const float*)d_in[19];
    const float* ln2_g             = (const float*)d_in[20];
    const float* ln2_b             = (const float*)d_in[21];
    float* out = (float*)d_out;

    u32* wpk = (u32*)d_ws;                 // 163840 B packed weights

    pack_weights<<<dim3(160), dim3(256), 0, stream>>>(Wl1, Wr1, Wl2, Wr2, Wl3, Wr3, wpk);
    gnn_fused<<<dim3(128), dim3(1024), 0, stream>>>(
        team_obs, target_obs, team_mask, local_target_mask, W_emb, b_emb,
        att1, b1, ln1_g, ln1_b, att2, b2, ln2_g, ln2_b, att3, b3, wpk, out);
}

// Round 10
// 138.621 us; speedup vs baseline: 1.0021x; 1.0021x over previous
//
#include <hip/hip_runtime.h>

typedef unsigned short u16;
typedef unsigned int   u32;
typedef _Float16 h2  __attribute__((ext_vector_type(2)));   // arithmetic type
typedef __fp16   hw2 __attribute__((ext_vector_type(2)));   // builtin boundary
typedef __fp16   hw8 __attribute__((ext_vector_type(8)));   // mfma operand
typedef float    f4  __attribute__((ext_vector_type(4)));   // mfma accumulator

// LDS row stride for sX / sXl in u16 elements: 136*2 = 272 B -> row starts 16B-aligned.
#define XS 136
#define PS 72    // sP   row stride (u16):  P[h][j][i], i contiguous (A-fragment ready)
#define BS 72    // sXlB row stride (u16):  xl^T[c][i], i contiguous (B-fragment ready)
#define OS 72    // sOutF row stride (f32): agg[c][j],  j contiguous (LN-read friendly)

static __device__ __forceinline__ h2 pk(float a, float b) {
    return __builtin_bit_cast(h2, __builtin_amdgcn_cvt_pkrtz(a, b));
}
static __device__ __forceinline__ float dot2(h2 a, h2 b, float c) {
    return __builtin_amdgcn_fdot2(__builtin_bit_cast(hw2, a),
                                  __builtin_bit_cast(hw2, b), c, false);   // v_dot2_f32_f16
}
static __device__ __forceinline__ h2  b2h(u32 v) { return __builtin_bit_cast(h2, v); }
static __device__ __forceinline__ u32 h2u(h2 v)  { return __builtin_bit_cast(u32, v); }
static __device__ __forceinline__ h2  abs2(h2 v) { return b2h(h2u(v) & 0x7fff7fffu); }
static __device__ __forceinline__ u16 f2h(float f) { return __builtin_bit_cast(u16, (_Float16)f); }
static __device__ __forceinline__ f4 mfma16(uint4 a, uint4 b, f4 c) {
    return __builtin_amdgcn_mfma_f32_16x16x32_f16(__builtin_bit_cast(hw8, a),
                                                  __builtin_bit_cast(hw8, b), c, 0, 0, 0);
}

// ---------------- K0: pack weights f32 -> MFMA B-fragment-ordered f16 ----------------
// wpk (u32): [0]=L1 [8192]=R1 [16384]=L2 [24576]=R2 [32768]=L3 [36864]=R3 ; 160 KB
__global__ void pack_weights(const float* __restrict__ Wl1, const float* __restrict__ Wr1,
                             const float* __restrict__ Wl2, const float* __restrict__ Wr2,
                             const float* __restrict__ Wl3, const float* __restrict__ Wr3,
                             u32* __restrict__ wpk)
{
    const int o = blockIdx.x * 256 + threadIdx.x;    // 0 .. 40959
    const float* src; u32* dst; int local; int N;
    if      (o < 8192)  { src = Wl1; dst = wpk;         local = o;         N = 128; }
    else if (o < 16384) { src = Wr1; dst = wpk + 8192;  local = o - 8192;  N = 128; }
    else if (o < 24576) { src = Wl2; dst = wpk + 16384; local = o - 16384; N = 128; }
    else if (o < 32768) { src = Wr2; dst = wpk + 24576; local = o - 24576; N = 128; }
    else if (o < 36864) { src = Wl3; dst = wpk + 32768; local = o - 32768; N = 64;  }
    else                { src = Wr3; dst = wpk + 36864; local = o - 36864; N = 64;  }
    const int i2   = local & 3;
    const int lane = (local >> 2) & 63;
    const int frag = local >> 8;
    const int kb   = frag & 3;
    const int nt   = frag >> 2;
    const int k0   = kb*32 + ((lane >> 4) << 3) + i2*2;
    const int n    = nt*16 + (lane & 15);
    dst[local] = h2u(pk(src[k0*N + n], src[(k0+1)*N + n]));
}

// ---------------- shared device pieces ----------------
static __device__ __forceinline__ void compute_imp(int t, int b,
    const float* __restrict__ team_mask, const float* __restrict__ ltm, float* sImp)
{
    if (t < 64) {
        float im;
        if (t < 16) im = (team_mask[b*32 + t] != -1000000000.0f) ? 1.f : 0.f;
        else        im = (ltm[b*49 + (t-16)] != 0.0f) ? 1.f : 0.f;
        sImp[t] = im;
    }
}

// full 128-col MFMA projection, 16 waves: mt = w&3, isR = (w>>2)&1, nt-half = w>>3.
static __device__ __forceinline__ void matmul128(int w, int lane,
    const u32* __restrict__ wpkL, const u32* __restrict__ wpkR,
    const u16* sX, u16* sXl, uint4* sXrP, u16* sXlB)
{
    const int  mt  = w & 3;
    const bool isR = (w >> 2) & 1;
    const int  nh  = w >> 3;
    const u32* wp  = isR ? wpkR : wpkL;
    const int  n15 = lane & 15;
    const int  qd  = lane >> 4;
    uint4 afr[4];
#pragma unroll
    for (int kb = 0; kb < 4; kb++)
        afr[kb] = *(const uint4*)&sX[(mt*16 + n15)*XS + kb*32 + (qd << 3)];
#pragma unroll 1
    for (int nt = nh*4; nt < nh*4 + 4; nt++) {
        f4 acc = {0.f, 0.f, 0.f, 0.f};
#pragma unroll
        for (int kb = 0; kb < 4; kb++) {
            uint4 bf = *(const uint4*)&wp[((nt*4 + kb)*64 + lane)*4];
            acc = mfma16(afr[kb], bf, acc);
        }
        const int n  = nt*16 + n15;
        const int mb = mt*16 + (qd << 2);
        if (!isR) {
#pragma unroll
            for (int r = 0; r < 4; r++) sXl[(mb + r)*XS + n] = f2h(acc[r]);
            uint2 u;
            u.x = h2u(pk(acc[0], acc[1]));
            u.y = h2u(pk(acc[2], acc[3]));
            *(uint2*)&sXlB[n*BS + mb] = u;
        } else {
            u16* xp = (u16*)sXrP;
#pragma unroll
            for (int r = 0; r < 4; r++)
                xp[(((n >> 3)*64) + mb + r)*8 + (n & 7)] = f2h(acc[r]);
        }
    }
}

// scores (H=4,C=32): thread (h = w&3, qf = w>>2, j = lane) computes p for 16 i's,
// stores packed f16 P-row chunks into sP[h][j][i], f32 denom partial into sL2.
static __device__ __forceinline__ void attn_scores(int w, int lane,
    const float* __restrict__ att,
    const u16* sXl, const uint4* sXrP, u16* sP,
    float* sAl, float* sL2, const float* sImp)
{
    const int h  = w & 3;
    const int qf = w >> 2;     // i-quarter 0..3
    const int j  = lane;

    h2 a2[16];
#pragma unroll
    for (int q = 0; q < 16; q++) a2[q] = pk(att[h*32 + 2*q], att[h*32 + 2*q + 1]);

    // Al[h][i] for all 64 i — waves 0-3, i = lane
    if (w < 4) {
        const uint4* pr = (const uint4*)&sXl[lane*XS + h*32];
        float al = 0.f;
#pragma unroll
        for (int c4 = 0; c4 < 4; c4++) {
            uint4 v = pr[c4];
            al = dot2(b2h(v.x), a2[c4*4+0], al);
            al = dot2(b2h(v.y), a2[c4*4+1], al);
            al = dot2(b2h(v.z), a2[c4*4+2], al);
            al = dot2(b2h(v.w), a2[c4*4+3], al);
        }
        sAl[h*64 + lane] = al;
    }

    h2 xr2[16];
#pragma unroll
    for (int s = 0; s < 4; s++) {
        uint4 v = sXrP[(h*4 + s)*64 + j];
        xr2[s*4+0] = b2h(v.x); xr2[s*4+1] = b2h(v.y);
        xr2[s*4+2] = b2h(v.z); xr2[s*4+3] = b2h(v.w);
    }
    float Ar = 0.f;
#pragma unroll
    for (int q = 0; q < 16; q++) Ar = dot2(a2[q], xr2[q], Ar);
    const float impj = sImp[j];
    __syncthreads();            // sAl ready

    float l = 0.f;
    uint2* pd = (uint2*)&sP[(h*64 + j)*PS + qf*16];
#pragma unroll 1
    for (int c8 = 0; c8 < 4; c8++) {          // rolled outer; all reg indices static inside
        u32 pr2[2];
        float pprev = 0.f;
#pragma unroll
        for (int i2 = 0; i2 < 4; i2++) {
            const int i = qf*16 + c8*4 + i2;
            const uint4* pl = (const uint4*)&sXl[i*XS + h*32];
            uint4 v0 = pl[0], v1 = pl[1], v2 = pl[2], v3 = pl[3];
            h2 xl2[16];
            xl2[0] = b2h(v0.x); xl2[1] = b2h(v0.y); xl2[2]  = b2h(v0.z); xl2[3]  = b2h(v0.w);
            xl2[4] = b2h(v1.x); xl2[5] = b2h(v1.y); xl2[6]  = b2h(v1.z); xl2[7]  = b2h(v1.w);
            xl2[8] = b2h(v2.x); xl2[9] = b2h(v2.y); xl2[10] = b2h(v2.z); xl2[11] = b2h(v2.w);
            xl2[12]= b2h(v3.x); xl2[13]= b2h(v3.y); xl2[14] = b2h(v3.z); xl2[15] = b2h(v3.w);
            float S0 = 0.f, S1 = 0.f;
#pragma unroll
            for (int q = 0; q < 16; q += 2) {
                h2 t0 = abs2(xl2[q]   + xr2[q]);
                h2 t1 = abs2(xl2[q+1] + xr2[q+1]);
                S0 = dot2(a2[q],   t0, S0);
                S1 = dot2(a2[q+1], t1, S1);
            }
            float e  = 0.6f*(sAl[h*64 + i] + Ar) + 0.4f*(S0 + S1);
            float ad = (i == j) ? 1.f : impj * sImp[i];
            float p  = (ad != 0.f) ? __expf(e) : 0.f;
            if (i2 & 1) {
                h2 pp = pk(pprev, p);
                pr2[i2 >> 1] = h2u(pp);
                l += (float)pp[0] + (float)pp[1];   // denom from the f16-rounded p (matches MFMA)
            } else {
                pprev = p;
            }
        }
        pd[c8] = make_uint2(pr2[0], pr2[1]);
    }
    sL2[h*256 + qf*64 + j] = l;
}

// MFMA aggregation out[j,c] = sum_i P[i,j]*xl[i,c] + LN + ReLU, writes activations to sXout.
// 16 waves: h = w&3, jq = w>>2 (j-tile); LN: wave w handles 8 channels for all 64 j.
static __device__ __forceinline__ void attn_agg_ln(int w, int lane,
    const float* __restrict__ bias, const float* __restrict__ lg, const float* __restrict__ lb,
    const u16* sP, const u16* sXlB, float* sOutF, const float* sL2,
    float* sPart, u16* sXout)
{
    const int h   = w & 3;
    const int jq  = w >> 2;
    const int n15 = lane & 15;
    const int kq  = lane >> 4;

    f4 acc0 = {0.f,0.f,0.f,0.f}, acc1 = acc0;
#pragma unroll
    for (int ks = 0; ks < 2; ks++) {
        uint4 af  = *(const uint4*)&sP[(h*64 + jq*16 + n15)*PS + ks*32 + kq*8];
        uint4 bf0 = *(const uint4*)&sXlB[(h*32 +  0 + n15)*BS + ks*32 + kq*8];
        uint4 bf1 = *(const uint4*)&sXlB[(h*32 + 16 + n15)*BS + ks*32 + kq*8];
        acc0 = mfma16(af, bf0, acc0);
        acc1 = mfma16(af, bf1, acc1);
    }
    {
        const int jb0 = jq*16 + kq*4;
#pragma unroll
        for (int r = 0; r < 4; r++) {
            sOutF[(h*32 +  0 + n15)*OS + jb0 + r] = acc0[r];
            sOutF[(h*32 + 16 + n15)*OS + jb0 + r] = acc1[r];
        }
    }
    __syncthreads();   // sOutF ready

    // LN: wave w handles channels w*8 .. +8 for all 64 j = lane
    const int cg = w, j = lane, hd = cg >> 2;
    const float l  = (sL2[hd*256 + j]       + sL2[hd*256 +  64 + j])
                   + (sL2[hd*256 + 128 + j] + sL2[hd*256 + 192 + j]);
    const float rl = 1.f / l;
    float y[8];
    float s1 = 0.f, s2 = 0.f;
#pragma unroll
    for (int k = 0; k < 8; k++) {
        float v = fmaf(sOutF[(cg*8 + k)*OS + j], rl, bias[cg*8 + k]);
        y[k] = v; s1 += v; s2 = fmaf(v, v, s2);
    }
    sPart[cg*64 + j]        = s1;
    sPart[1024 + cg*64 + j] = s2;
    __syncthreads();
    float su = 0.f, sq = 0.f;
#pragma unroll
    for (int p = 0; p < 16; p++) { su += sPart[p*64 + j]; sq += sPart[1024 + p*64 + j]; }
    const float mean = su * 0.0078125f;
    const float var  = sq * 0.0078125f - mean*mean;
    const float rstd = rsqrtf(var + 1e-5f);
    u32* xo = (u32*)&sXout[j*XS];
#pragma unroll
    for (int q = 0; q < 4; q++) {
        const int c0 = cg*8 + 2*q;
        float v0 = fmaxf(fmaf((y[2*q]   - mean)*rstd, lg[c0],   lb[c0]),   0.f);
        float v1 = fmaxf(fmaf((y[2*q+1] - mean)*rstd, lg[c0+1], lb[c0+1]), 0.f);
        xo[cg*4 + q] = h2u(pk(v0, v1));
    }
}

// ---------------- fused kernel: embed + GAT1 + GAT2 + GAT3, one block per batch ----------------
__global__ void __launch_bounds__(1024, 4) gnn_fused(
    const float* __restrict__ team_obs, const float* __restrict__ target_obs,
    const float* __restrict__ team_mask, const float* __restrict__ ltm,
    const float* __restrict__ W_emb, const float* __restrict__ b_emb,
    const float* __restrict__ att1, const float* __restrict__ b1,
    const float* __restrict__ ln1_g, const float* __restrict__ ln1_b,
    const float* __restrict__ att2, const float* __restrict__ b2,
    const float* __restrict__ ln2_g, const float* __restrict__ ln2_b,
    const float* __restrict__ att3, const float* __restrict__ b3,
    const u32* __restrict__ wpk, float* __restrict__ out)
{
    __shared__ __align__(16) u16   sX  [64*XS];    // activations (layer input)
    __shared__ __align__(16) u16   sXl [64*XS];    // xl projection, row-major
    __shared__ __align__(16) uint4 sXrP[1024];     // xr projection, packed per node
    __shared__ __align__(16) u16   sXlB[128*BS];   // xl^T col-major (MFMA B-frags)
    __shared__ __align__(16) u16   sP  [4*64*PS];  // P[h][j][i] f16 (MFMA A-frags); sFin overlay
    __shared__ __align__(16) float sOutF[128*OS];  // f32 aggregation output [c][j]
    __shared__ float sAl [256];
    __shared__ float sPart[2048];
    __shared__ float sL2 [1024];
    __shared__ float sImp[64];

    const int t    = threadIdx.x;
    const int w    = t >> 6;
    const int lane = t & 63;
    const int b    = blockIdx.x;                   // one batch per block

    float* sFin = (float*)sP;                      // 4 KB overlay, embed phase only

    compute_imp(t, b, team_mask, ltm, sImp);
    {
        int m = t >> 4, k = t & 15;                // 1024 threads -> all 64x16 elements
        float v = 0.f;
        if (m < 16) {
            if (k < 14) v = team_obs[(b*16 + m)*14 + k];
        } else {
            const float* tg = target_obs + (size_t)(b*48 + (m-16))*15;
            if      (k < 12)  v = tg[k];
            else if (k == 14) v = tg[12];
            else if (k == 15) v = tg[13];
        }
        sFin[m*16 + k] = v;
    }
    __syncthreads();

    // embed: x = fin @ W_emb + b_emb -> sX (f16); 8 groups x 8 rows
    {
        const int f = t & 127;
        const int g = t >> 7;
        float wreg[16];
#pragma unroll
        for (int k = 0; k < 16; k++) wreg[k] = W_emb[k*128 + f];
        const float bf = b_emb[f];
#pragma unroll 1
        for (int mm = 0; mm < 8; mm++) {
            int m = g*8 + mm;
            const float4* pf = (const float4*)&sFin[m*16];
            float4 f0 = pf[0], f1 = pf[1], f2 = pf[2], f3 = pf[3];
            float acc = bf;
            acc = fmaf(f0.x, wreg[0],  acc); acc = fmaf(f0.y, wreg[1],  acc);
            acc = fmaf(f0.z, wreg[2],  acc); acc = fmaf(f0.w, wreg[3],  acc);
            acc = fmaf(f1.x, wreg[4],  acc); acc = fmaf(f1.y, wreg[5],  acc);
            acc = fmaf(f1.z, wreg[6],  acc); acc = fmaf(f1.w, wreg[7],  acc);
            acc = fmaf(f2.x, wreg[8],  acc); acc = fmaf(f2.y, wreg[9],  acc);
            acc = fmaf(f2.z, wreg[10], acc); acc = fmaf(f2.w, wreg[11], acc);
            acc = fmaf(f3.x, wreg[12], acc); acc = fmaf(f3.y, wreg[13], acc);
            acc = fmaf(f3.z, wreg[14], acc); acc = fmaf(f3.w, wreg[15], acc);
            sX[m*XS + f] = f2h(acc);
        }
    }
    __syncthreads();

    // -------- layers 1 & 2: SINGLE emitted body, looped (code-size experiment) --------
#pragma unroll 1
    for (int L = 0; L < 2; ++L) {
        const u32*   wl = (L == 0) ? wpk          : wpk + 16384;
        const u32*   wr = (L == 0) ? wpk + 8192   : wpk + 24576;
        const float* at = (L == 0) ? att1  : att2;
        const float* bi = (L == 0) ? b1    : b2;
        const float* lg = (L == 0) ? ln1_g : ln2_g;
        const float* lb = (L == 0) ? ln1_b : ln2_b;

        matmul128(w, lane, wl, wr, sX, sXl, sXrP, sXlB);
        __syncthreads();
        attn_scores(w, lane, at, sXl, sXrP, sP, sAl, sL2, sImp);
        __syncthreads();
        attn_agg_ln(w, lane, bi, lg, lb, sP, sXlB, sOutF, sL2, sPart, sX);
        __syncthreads();
    }

    // -------- layer 3 (H=1, C=64) --------
    {
        const int  mt  = w & 3;
        const bool isR = (w >> 2) & 1;
        const int  nh  = w >> 3;
        const u32* wp  = isR ? (wpk + 36864) : (wpk + 32768);
        const int  n15 = lane & 15;
        const int  qd  = lane >> 4;
        uint4 afr[4];
#pragma unroll
        for (int kb = 0; kb < 4; kb++)
            afr[kb] = *(const uint4*)&sX[(mt*16 + n15)*XS + kb*32 + (qd << 3)];
#pragma unroll 1
        for (int nt = nh*2; nt < nh*2 + 2; nt++) {
            f4 acc = {0.f, 0.f, 0.f, 0.f};
#pragma unroll
            for (int kb = 0; kb < 4; kb++) {
                uint4 bf = *(const uint4*)&wp[((nt*4 + kb)*64 + lane)*4];
                acc = mfma16(afr[kb], bf, acc);
            }
            const int n  = nt*16 + n15;
            const int mb = mt*16 + (qd << 2);
            if (!isR) {
#pragma unroll
                for (int r = 0; r < 4; r++) sXl[(mb + r)*XS + n] = f2h(acc[r]);
                uint2 u;
                u.x = h2u(pk(acc[0], acc[1]));
                u.y = h2u(pk(acc[2], acc[3]));
                *(uint2*)&sXlB[n*BS + mb] = u;
            } else {
                u16* xp = (u16*)sXrP;
#pragma unroll
                for (int r = 0; r < 4; r++)
                    xp[(((n >> 3)*64) + mb + r)*8 + (n & 7)] = f2h(acc[r]);
            }
        }
    }
    __syncthreads();

    // Al3[i] (16-way c-split: 4 channels per wave)
    {
        h2 a2l[2];
        a2l[0] = pk(att3[w*4 + 0], att3[w*4 + 1]);
        a2l[1] = pk(att3[w*4 + 2], att3[w*4 + 3]);
        uint2 v = *(const uint2*)&sXl[lane*XS + w*4];
        float al = dot2(b2h(v.x), a2l[0], 0.f);
        al = dot2(b2h(v.y), a2l[1], al);
        sPart[w*64 + lane] = al;
    }
    __syncthreads();
    if (t < 64) {
        float s = 0.f;
#pragma unroll
        for (int p = 0; p < 16; p += 4)
            s += ((sPart[p*64 + t] + sPart[(p+1)*64 + t]) +
                  (sPart[(p+2)*64 + t] + sPart[(p+3)*64 + t]));
        sAl[t] = s;
    }
    __syncthreads();

    // scores3: thread (w, j=lane) handles 4 i's; stores p (f16) into sP[j][i], denom partial.
    {
        h2 a3[32], xr3[32];
#pragma unroll
        for (int q = 0; q < 32; q++) a3[q] = pk(att3[2*q], att3[2*q + 1]);
#pragma unroll
        for (int s = 0; s < 8; s++) {
            uint4 v = sXrP[s*64 + lane];
            xr3[s*4+0] = b2h(v.x); xr3[s*4+1] = b2h(v.y);
            xr3[s*4+2] = b2h(v.z); xr3[s*4+3] = b2h(v.w);
        }
        float Ar = 0.f;
#pragma unroll
        for (int q = 0; q < 32; q++) Ar = dot2(a3[q], xr3[q], Ar);
        const float impj = sImp[lane];
        float l3 = 0.f;
        u32 pr2[2];
        float pprev = 0.f;
#pragma unroll
        for (int ii = 0; ii < 4; ii++) {
            const int i = w*4 + ii;
            const uint4* pl = (const uint4*)&sXl[i*XS];
            float S0 = 0.f, S1 = 0.f;
#pragma unroll
            for (int c4 = 0; c4 < 8; c4++) {
                uint4 v = pl[c4];
                S0 = dot2(a3[c4*4+0], abs2(b2h(v.x) + xr3[c4*4+0]), S0);
                S1 = dot2(a3[c4*4+1], abs2(b2h(v.y) + xr3[c4*4+1]), S1);
                S0 = dot2(a3[c4*4+2], abs2(b2h(v.z) + xr3[c4*4+2]), S0);
                S1 = dot2(a3[c4*4+3], abs2(b2h(v.w) + xr3[c4*4+3]), S1);
            }
            float e  = 0.6f*(sAl[i] + Ar) + 0.4f*(S0 + S1);
            float ad = (i == lane) ? 1.f : impj * sImp[i];
            float p  = (ad != 0.f) ? __expf(e) : 0.f;
            if (ii & 1) {
                h2 pp = pk(pprev, p);
                pr2[ii >> 1] = h2u(pp);
                l3 += (float)pp[0] + (float)pp[1];
            } else {
                pprev = p;
            }
        }
        *(uint2*)&sP[lane*PS + w*4] = make_uint2(pr2[0], pr2[1]);
        sPart[w*64 + lane] = l3;
    }
    __syncthreads();
    if (t < 64) {
        float s = 0.f;
#pragma unroll
        for (int p = 0; p < 16; p += 4)
            s += ((sPart[p*64 + t] + sPart[(p+1)*64 + t]) +
                  (sPart[(p+2)*64 + t] + sPart[(p+3)*64 + t]));
        sL2[t] = 1.f / s;
    }

    // agg3 via MFMA: out[j,c] = sum_i P3[i,j]*xl3[i,c]; 16 waves: jt = w&3, ct = w>>2
    {
        const int jt  = w & 3;
        const int ct  = w >> 2;
        const int n15 = lane & 15;
        const int kq  = lane >> 4;
        f4 acc = {0.f,0.f,0.f,0.f};
#pragma unroll
        for (int ks = 0; ks < 2; ks++) {
            uint4 af = *(const uint4*)&sP[(jt*16 + n15)*PS + ks*32 + kq*8];
            uint4 bf = *(const uint4*)&sXlB[(ct*16 + n15)*BS + ks*32 + kq*8];
            acc = mfma16(af, bf, acc);
        }
        __syncthreads();   // sL2 (1/l) ready
        const int c  = ct*16 + n15;
        const float bc = b3[c];
#pragma unroll
        for (int r = 0; r < 4; r++) {
            const int jj = jt*16 + kq*4 + r;
            out[(size_t)b*4096 + (size_t)jj*64 + c] = fmaf(acc[r], sL2[jj], bc);
        }
    }
}

extern "C" void kernel_launch(void* const* d_in, const int* in_sizes, int n_in,
                              void* d_out, int out_size, void* d_ws, size_t ws_size,
                              hipStream_t stream) {
    (void)in_sizes; (void)n_in; (void)ws_size; (void)out_size;
    const float* team_obs          = (const float*)d_in[0];
    const float* target_obs        = (const float*)d_in[1];
    const float* team_mask         = (const float*)d_in[2];
    const float* local_target_mask = (const float*)d_in[3];
    const float* W_emb             = (const float*)d_in[4];
    const float* b_emb             = (const float*)d_in[5];
    const float* Wl1               = (const float*)d_in[6];
    const float* Wr1               = (const float*)d_in[7];
    const float* att1              = (const float*)d_in[8];
    const float* b1                = (const float*)d_in[9];
    const float* Wl2               = (const float*)d_in[10];
    const float* Wr2               = (const float*)d_in[11];
    const float* att2              = (const float*)d_in[12];
    const float* b2                = (const float*)d_in[13];
    const float* Wl3               = (const float*)d_in[14];
    const float* Wr3               = (const float*)d_in[15];
    const float* att3              = (const float*)d_in[16];
    const float* b3                = (const float*)d_in[17];
    const float* ln1_g             = (const float*)d_in[18];
    const float* ln1_b             = (const float*)d_in[19];
    const float* ln2_g             = (const float*)d_in[20];
    const float* ln2_b             = (const float*)d_in[21];
    float* out = (float*)d_out;

    u32* wpk = (u32*)d_ws;                 // 163840 B packed weights

    pack_weights<<<dim3(160), dim3(256), 0, stream>>>(Wl1, Wr1, Wl2, Wr2, Wl3, Wr3, wpk);
    gnn_fused<<<dim3(128), dim3(1024), 0, stream>>>(
        team_obs, target_obs, team_mask, local_target_mask, W_emb, b_emb,
        att1, b1, ln1_g, ln1_b, att2, b2, ln2_g, ln2_b, att3, b3, wpk, out);
}

// Round 11
// 131.962 us; speedup vs baseline: 1.0526x; 1.0505x over previous
//
#include <hip/hip_runtime.h>

typedef unsigned short u16;
typedef unsigned int   u32;
typedef _Float16 h2  __attribute__((ext_vector_type(2)));   // arithmetic type
typedef __fp16   hw2 __attribute__((ext_vector_type(2)));   // builtin boundary
typedef __fp16   hw8 __attribute__((ext_vector_type(8)));   // mfma operand
typedef float    f4  __attribute__((ext_vector_type(4)));   // mfma accumulator

// LDS strides (u16 elements unless noted)
#define XS 136   // sX / sXl rows: 128 ch + pad -> 272 B, 16B-aligned
#define PS 72    // sP rows:  P[h][jj][i], 64 i + pad
#define BS 72    // sXlB rows: xl^T[c][i], 64 i + pad
#define OS2 20   // sOutF rows (f32): agg[c][jj], 16 j + pad

static __device__ __forceinline__ h2 pk(float a, float b) {
    return __builtin_bit_cast(h2, __builtin_amdgcn_cvt_pkrtz(a, b));
}
static __device__ __forceinline__ float dot2(h2 a, h2 b, float c) {
    return __builtin_amdgcn_fdot2(__builtin_bit_cast(hw2, a),
                                  __builtin_bit_cast(hw2, b), c, false);   // v_dot2_f32_f16
}
static __device__ __forceinline__ h2  b2h(u32 v) { return __builtin_bit_cast(h2, v); }
static __device__ __forceinline__ u32 h2u(h2 v)  { return __builtin_bit_cast(u32, v); }
static __device__ __forceinline__ h2  abs2(h2 v) { return b2h(h2u(v) & 0x7fff7fffu); }
static __device__ __forceinline__ u16 f2h(float f) { return __builtin_bit_cast(u16, (_Float16)f); }
static __device__ __forceinline__ f4 mfma16(uint4 a, uint4 b, f4 c) {
    return __builtin_amdgcn_mfma_f32_16x16x32_f16(__builtin_bit_cast(hw8, a),
                                                  __builtin_bit_cast(hw8, b), c, 0, 0, 0);
}

// ---------------- K0: pack weights f32 -> MFMA B-fragment-ordered f16 ----------------
// wpk (u32): [0]=L1 [8192]=R1 [16384]=L2 [24576]=R2 [32768]=L3 [36864]=R3 ; 160 KB
__global__ void pack_weights(const float* __restrict__ Wl1, const float* __restrict__ Wr1,
                             const float* __restrict__ Wl2, const float* __restrict__ Wr2,
                             const float* __restrict__ Wl3, const float* __restrict__ Wr3,
                             u32* __restrict__ wpk)
{
    const int o = blockIdx.x * 256 + threadIdx.x;    // 0 .. 40959
    const float* src; u32* dst; int local; int N;
    if      (o < 8192)  { src = Wl1; dst = wpk;         local = o;         N = 128; }
    else if (o < 16384) { src = Wr1; dst = wpk + 8192;  local = o - 8192;  N = 128; }
    else if (o < 24576) { src = Wl2; dst = wpk + 16384; local = o - 16384; N = 128; }
    else if (o < 32768) { src = Wr2; dst = wpk + 24576; local = o - 24576; N = 128; }
    else if (o < 36864) { src = Wl3; dst = wpk + 32768; local = o - 32768; N = 64;  }
    else                { src = Wr3; dst = wpk + 36864; local = o - 36864; N = 64;  }
    const int i2   = local & 3;
    const int lane = (local >> 2) & 63;
    const int frag = local >> 8;
    const int kb   = frag & 3;
    const int nt   = frag >> 2;
    const int k0   = kb*32 + ((lane >> 4) << 3) + i2*2;
    const int n    = nt*16 + (lane & 15);
    dst[local] = h2u(pk(src[k0*N + n], src[(k0+1)*N + n]));
}

// ---------------- shared device pieces ----------------
static __device__ __forceinline__ void compute_imp(int t, int b,
    const float* __restrict__ team_mask, const float* __restrict__ ltm, float* sImp)
{
    if (t < 64) {
        float im;
        if (t < 16) im = (team_mask[b*32 + t] != -1000000000.0f) ? 1.f : 0.f;
        else        im = (ltm[b*49 + (t-16)] != 0.0f) ? 1.f : 0.f;
        sImp[t] = im;
    }
}

static __device__ __forceinline__ void load_afr_lds(const u16* sX, int mt, int lane, uint4 afr[4]) {
    const int n15 = lane & 15, qd = lane >> 4;
#pragma unroll
    for (int kb = 0; kb < 4; kb++)
        afr[kb] = *(const uint4*)&sX[(mt*16 + n15)*XS + kb*32 + (qd << 3)];
}
static __device__ __forceinline__ void load_afr_glb(const u32* __restrict__ gxRow, int mt, int lane, uint4 afr[4]) {
    const int n15 = lane & 15, qd = lane >> 4;
    const int m = mt*16 + n15;
#pragma unroll
    for (int kb = 0; kb < 4; kb++)
        afr[kb] = *(const uint4*)&gxRow[m*64 + kb*16 + qd*4];
}

// xl = x @ Wl (full 64 nodes x 128 ch); 8 waves: mt = w&3, nh = w>>2 (nt-half)
static __device__ __forceinline__ void projL128(int w, int lane, const u32* __restrict__ wp,
    const uint4 afr[4], u16* sXl, u16* sXlB)
{
    const int mt = w & 3, nh = w >> 2;
    const int n15 = lane & 15, qd = lane >> 4;
#pragma unroll
    for (int nt = nh*4; nt < nh*4 + 4; nt++) {
        f4 acc = {0.f, 0.f, 0.f, 0.f};
#pragma unroll
        for (int kb = 0; kb < 4; kb++) {
            uint4 bf = *(const uint4*)&wp[((nt*4 + kb)*64 + lane)*4];
            acc = mfma16(afr[kb], bf, acc);
        }
        const int n  = nt*16 + n15;
        const int mb = mt*16 + (qd << 2);
#pragma unroll
        for (int r = 0; r < 4; r++) sXl[(mb + r)*XS + n] = f2h(acc[r]);
        uint2 u;
        u.x = h2u(pk(acc[0], acc[1]));
        u.y = h2u(pk(acc[2], acc[3]));
        *(uint2*)&sXlB[n*BS + mb] = u;
    }
}

// xr = x @ Wr, ONLY this block's 16 nodes (m-tile q); 8 waves: nt = w
static __device__ __forceinline__ void projR16(int w, int lane, const u32* __restrict__ wp,
    const uint4 afq[4], u16* sXrPx)
{
    const int n15 = lane & 15, qd = lane >> 4;
    const int nt = w;
    f4 acc = {0.f, 0.f, 0.f, 0.f};
#pragma unroll
    for (int kb = 0; kb < 4; kb++) {
        uint4 bf = *(const uint4*)&wp[((nt*4 + kb)*64 + lane)*4];
        acc = mfma16(afq[kb], bf, acc);
    }
    const int n = nt*16 + n15;
#pragma unroll
    for (int r = 0; r < 4; r++)
        sXrPx[((n >> 3)*16 + (qd << 2) + r)*8 + (n & 7)] = f2h(acc[r]);
}

// scores (H=4,C=32) for this block's 16 dst nodes; 8 waves: h = w&3, qh = w>>2;
// lanes: jj = lane&15, is = lane>>4 -> 8 i's per thread.
static __device__ __forceinline__ void scores16(int w, int lane, int j0,
    const float* __restrict__ att,
    const u16* sXl, const u16* sXrPx, u16* sP,
    float* sAl, float* sL2, const float* sImp)
{
    const int h  = w & 3;
    const int qh = w >> 2;
    const int jj = lane & 15;
    const int is = lane >> 4;
    const int j  = j0 + jj;

    h2 a2[16];
#pragma unroll
    for (int q = 0; q < 16; q++) a2[q] = pk(att[h*32 + 2*q], att[h*32 + 2*q + 1]);

    // Al[h][i] for all 64 i — waves 0-3, i = lane
    if (w < 4) {
        const uint4* pr = (const uint4*)&sXl[lane*XS + h*32];
        float al = 0.f;
#pragma unroll
        for (int c4 = 0; c4 < 4; c4++) {
            uint4 v = pr[c4];
            al = dot2(b2h(v.x), a2[c4*4+0], al);
            al = dot2(b2h(v.y), a2[c4*4+1], al);
            al = dot2(b2h(v.z), a2[c4*4+2], al);
            al = dot2(b2h(v.w), a2[c4*4+3], al);
        }
        sAl[h*64 + lane] = al;
    }

    h2 xr2[16];
#pragma unroll
    for (int s = 0; s < 4; s++) {
        uint4 v = *(const uint4*)&sXrPx[((h*4 + s)*16 + jj)*8];
        xr2[s*4+0] = b2h(v.x); xr2[s*4+1] = b2h(v.y);
        xr2[s*4+2] = b2h(v.z); xr2[s*4+3] = b2h(v.w);
    }
    float Ar = 0.f;
#pragma unroll
    for (int q = 0; q < 16; q++) Ar = dot2(a2[q], xr2[q], Ar);
    const float impj = sImp[j];
    __syncthreads();            // sAl ready

    float l = 0.f;
    u32 pr4[4];
    float pprev = 0.f;
#pragma unroll
    for (int i2 = 0; i2 < 8; i2++) {
        const int i = qh*32 + is*8 + i2;
        const uint4* pl = (const uint4*)&sXl[i*XS + h*32];
        uint4 v0 = pl[0], v1 = pl[1], v2 = pl[2], v3 = pl[3];
        h2 xl2[16];
        xl2[0] = b2h(v0.x); xl2[1] = b2h(v0.y); xl2[2]  = b2h(v0.z); xl2[3]  = b2h(v0.w);
        xl2[4] = b2h(v1.x); xl2[5] = b2h(v1.y); xl2[6]  = b2h(v1.z); xl2[7]  = b2h(v1.w);
        xl2[8] = b2h(v2.x); xl2[9] = b2h(v2.y); xl2[10] = b2h(v2.z); xl2[11] = b2h(v2.w);
        xl2[12]= b2h(v3.x); xl2[13]= b2h(v3.y); xl2[14] = b2h(v3.z); xl2[15] = b2h(v3.w);
        float S0 = 0.f, S1 = 0.f;
#pragma unroll
        for (int q = 0; q < 16; q += 2) {
            h2 t0 = abs2(xl2[q]   + xr2[q]);
            h2 t1 = abs2(xl2[q+1] + xr2[q+1]);
            S0 = dot2(a2[q],   t0, S0);
            S1 = dot2(a2[q+1], t1, S1);
        }
        float e  = 0.6f*(sAl[h*64 + i] + Ar) + 0.4f*(S0 + S1);
        float ad = (i == j) ? 1.f : impj * sImp[i];
        float p  = (ad != 0.f) ? __expf(e) : 0.f;
        if (i2 & 1) {
            h2 pp = pk(pprev, p);
            pr4[i2 >> 1] = h2u(pp);
            l += (float)pp[0] + (float)pp[1];   // denom from f16-rounded p (matches MFMA)
        } else {
            pprev = p;
        }
    }
    *(uint4*)&sP[(h*16 + jj)*PS + qh*32 + is*8] = make_uint4(pr4[0], pr4[1], pr4[2], pr4[3]);
    sL2[((h*2 + qh)*4 + is)*16 + jj] = l;
}

// MFMA aggregation + bias + LN + ReLU for 16 dst nodes; writes f16 activations to global gxOut.
// 8 waves: h = w&3, cb = w>>2 (16-ch tile); LN: wave w = ch-group of 16, thread = (is2,jj) 4 ch.
static __device__ __forceinline__ void aggln16(int w, int lane, int b, int j0,
    const float* __restrict__ bias, const float* __restrict__ lg, const float* __restrict__ lb,
    const u16* sP, const u16* sXlB, float* sOutF, const float* sL2,
    float* sPart, u32* __restrict__ gxOut)
{
    const int h   = w & 3;
    const int cb  = w >> 2;
    const int n15 = lane & 15;
    const int kq  = lane >> 4;

    f4 acc = {0.f,0.f,0.f,0.f};
#pragma unroll
    for (int ks = 0; ks < 2; ks++) {
        uint4 af = *(const uint4*)&sP[(h*16 + n15)*PS + ks*32 + kq*8];
        uint4 bf = *(const uint4*)&sXlB[(h*32 + cb*16 + n15)*BS + ks*32 + kq*8];
        acc = mfma16(af, bf, acc);
    }
#pragma unroll
    for (int r = 0; r < 4; r++)
        sOutF[(h*32 + cb*16 + n15)*OS2 + kq*4 + r] = acc[r];
    __syncthreads();   // sOutF ready

    // LN: thread (w, is2, jj): channels w*16 + is2*4 .. +4 for node jj
    const int jj = lane & 15, is2 = lane >> 4, hd = w >> 1;
    float l = 0.f;
#pragma unroll
    for (int g = 0; g < 8; g++) l += sL2[(hd*8 + g)*16 + jj];
    const float rl = 1.f / l;
    const int c0 = w*16 + is2*4;
    float y[4];
    float s1 = 0.f, s2 = 0.f;
#pragma unroll
    for (int k = 0; k < 4; k++) {
        float v = fmaf(sOutF[(c0 + k)*OS2 + jj], rl, bias[c0 + k]);
        y[k] = v; s1 += v; s2 = fmaf(v, v, s2);
    }
    sPart[(w*4 + is2)*16 + jj]       = s1;
    sPart[512 + (w*4 + is2)*16 + jj] = s2;
    __syncthreads();
    float su = 0.f, sq = 0.f;
#pragma unroll
    for (int g = 0; g < 32; g++) { su += sPart[g*16 + jj]; sq += sPart[512 + g*16 + jj]; }
    const float mean = su * 0.0078125f;
    const float var  = sq * 0.0078125f - mean*mean;
    const float rstd = rsqrtf(var + 1e-5f);
    float v0 = fmaxf(fmaf((y[0] - mean)*rstd, lg[c0],   lb[c0]),   0.f);
    float v1 = fmaxf(fmaf((y[1] - mean)*rstd, lg[c0+1], lb[c0+1]), 0.f);
    float v2 = fmaxf(fmaf((y[2] - mean)*rstd, lg[c0+2], lb[c0+2]), 0.f);
    float v3 = fmaxf(fmaf((y[3] - mean)*rstd, lg[c0+3], lb[c0+3]), 0.f);
    uint2 o;
    o.x = h2u(pk(v0, v1));
    o.y = h2u(pk(v2, v3));
    *(uint2*)(gxOut + (size_t)b*4096 + (size_t)(j0 + jj)*64 + (c0 >> 1)) = o;
}

// ---------------- kernel 1: embed + GAT layer 1 (grid 512: b = bid&127, q = bid>>7) ----------------
__global__ void __launch_bounds__(512, 4) gnn_l1(
    const float* __restrict__ team_obs, const float* __restrict__ target_obs,
    const float* __restrict__ team_mask, const float* __restrict__ ltm,
    const float* __restrict__ W_emb, const float* __restrict__ b_emb,
    const float* __restrict__ att1, const float* __restrict__ b1,
    const float* __restrict__ ln1_g, const float* __restrict__ ln1_b,
    const u32* __restrict__ wpk, u32* __restrict__ gx1)
{
    __shared__ __align__(16) u16 sX   [64*XS];
    __shared__ __align__(16) u16 sXl  [64*XS];
    __shared__ __align__(16) u16 sXlB [128*BS];
    __shared__ __align__(16) u16 sXrPx[2048];
    __shared__ __align__(16) u16 sP   [4*16*PS];
    __shared__ float sAl [256];
    __shared__ float sL2 [512];
    __shared__ float sPart[1024];
    __shared__ float sImp[64];

    const int t    = threadIdx.x;
    const int w    = t >> 6;
    const int lane = t & 63;
    const int b    = blockIdx.x & 127;
    const int q    = blockIdx.x >> 7;     // j-quarter
    const int j0   = q*16;

    float* sFin  = (float*)sP;            // overlay: embed input, dead before sP use
    float* sOutF = (float*)sX;            // overlay: agg output, sX dead after projections

    compute_imp(t, b, team_mask, ltm, sImp);
    for (int ee = t; ee < 1024; ee += 512) {
        int m = ee >> 4, k = ee & 15;
        float v = 0.f;
        if (m < 16) {
            if (k < 14) v = team_obs[(b*16 + m)*14 + k];
        } else {
            const float* tg = target_obs + (size_t)(b*48 + (m-16))*15;
            if      (k < 12)  v = tg[k];
            else if (k == 14) v = tg[12];
            else if (k == 15) v = tg[13];
        }
        sFin[m*16 + k] = v;
    }
    __syncthreads();

    // embed: x = fin @ W_emb + b_emb -> sX (f16)
    {
        const int f = t & 127;
        const int g = t >> 7;
        float wreg[16];
#pragma unroll
        for (int k = 0; k < 16; k++) wreg[k] = W_emb[k*128 + f];
        const float bf = b_emb[f];
#pragma unroll
        for (int mm = 0; mm < 16; mm++) {
            int m = g*16 + mm;
            const float4* pf = (const float4*)&sFin[m*16];
            float4 f0 = pf[0], f1 = pf[1], f2 = pf[2], f3 = pf[3];
            float acc = bf;
            acc = fmaf(f0.x, wreg[0],  acc); acc = fmaf(f0.y, wreg[1],  acc);
            acc = fmaf(f0.z, wreg[2],  acc); acc = fmaf(f0.w, wreg[3],  acc);
            acc = fmaf(f1.x, wreg[4],  acc); acc = fmaf(f1.y, wreg[5],  acc);
            acc = fmaf(f1.z, wreg[6],  acc); acc = fmaf(f1.w, wreg[7],  acc);
            acc = fmaf(f2.x, wreg[8],  acc); acc = fmaf(f2.y, wreg[9],  acc);
            acc = fmaf(f2.z, wreg[10], acc); acc = fmaf(f2.w, wreg[11], acc);
            acc = fmaf(f3.x, wreg[12], acc); acc = fmaf(f3.y, wreg[13], acc);
            acc = fmaf(f3.z, wreg[14], acc); acc = fmaf(f3.w, wreg[15], acc);
            sX[m*XS + f] = f2h(acc);
        }
    }
    __syncthreads();

    uint4 afr[4], afq[4];
    load_afr_lds(sX, w & 3, lane, afr);
    load_afr_lds(sX, q,     lane, afq);
    projL128(w, lane, wpk,        afr, sXl, sXlB);
    projR16 (w, lane, wpk + 8192, afq, sXrPx);
    __syncthreads();

    scores16(w, lane, j0, att1, sXl, sXrPx, sP, sAl, sL2, sImp);
    __syncthreads();
    aggln16(w, lane, b, j0, b1, ln1_g, ln1_b, sP, sXlB, sOutF, sL2, sPart, gx1);
}

// ---------------- kernel 2: GAT layer 2 (A-frags from gx1) ----------------
__global__ void __launch_bounds__(512, 4) gnn_l2(
    const float* __restrict__ team_mask, const float* __restrict__ ltm,
    const float* __restrict__ att2, const float* __restrict__ b2,
    const float* __restrict__ ln2_g, const float* __restrict__ ln2_b,
    const u32* __restrict__ wpk, const u32* __restrict__ gxIn, u32* __restrict__ gxOut)
{
    __shared__ __align__(16) u16 sXl  [64*XS];
    __shared__ __align__(16) u16 sXlB [128*BS];
    __shared__ __align__(16) u16 sXrPx[2048];
    __shared__ __align__(16) u16 sP   [4*16*PS];
    __shared__ __align__(16) float sOutF[128*OS2];
    __shared__ float sAl [256];
    __shared__ float sL2 [512];
    __shared__ float sPart[1024];
    __shared__ float sImp[64];

    const int t    = threadIdx.x;
    const int w    = t >> 6;
    const int lane = t & 63;
    const int b    = blockIdx.x & 127;
    const int q    = blockIdx.x >> 7;
    const int j0   = q*16;

    compute_imp(t, b, team_mask, ltm, sImp);
    const u32* gxRow = gxIn + (size_t)b*4096;

    uint4 afr[4], afq[4];
    load_afr_glb(gxRow, w & 3, lane, afr);
    load_afr_glb(gxRow, q,     lane, afq);
    projL128(w, lane, wpk + 16384, afr, sXl, sXlB);
    projR16 (w, lane, wpk + 24576, afq, sXrPx);
    __syncthreads();

    scores16(w, lane, j0, att2, sXl, sXrPx, sP, sAl, sL2, sImp);
    __syncthreads();
    aggln16(w, lane, b, j0, b2, ln2_g, ln2_b, sP, sXlB, sOutF, sL2, sPart, gxOut);
}

// ---------------- kernel 3: GAT layer 3 (H=1, C=64) + output ----------------
__global__ void __launch_bounds__(512, 4) gnn_l3(
    const float* __restrict__ team_mask, const float* __restrict__ ltm,
    const float* __restrict__ att3, const float* __restrict__ b3,
    const u32* __restrict__ wpk, const u32* __restrict__ gxIn, float* __restrict__ out)
{
    __shared__ __align__(16) u16 sXl3 [64*72];
    __shared__ __align__(16) u16 sXlB3[64*72];
    __shared__ __align__(16) u16 sXrP3[1024];
    __shared__ __align__(16) u16 sP3  [16*72];
    __shared__ float sAl3[64];
    __shared__ float sPart[512];
    __shared__ float sRl [16];
    __shared__ float sImp[64];

    const int t    = threadIdx.x;
    const int w    = t >> 6;
    const int lane = t & 63;
    const int b    = blockIdx.x & 127;
    const int q    = blockIdx.x >> 7;
    const int j0   = q*16;
    const int n15  = lane & 15;
    const int qd   = lane >> 4;

    compute_imp(t, b, team_mask, ltm, sImp);
    const u32* gxRow = gxIn + (size_t)b*4096;

    // L projection (C=64): 8 waves: mt = w&3, nh = w>>2 -> nt = nh*2..+2
    {
        uint4 afr[4];
        load_afr_glb(gxRow, w & 3, lane, afr);
        const u32* wp = wpk + 32768;
        const int mt = w & 3, nh = w >> 2;
#pragma unroll
        for (int nt = nh*2; nt < nh*2 + 2; nt++) {
            f4 acc = {0.f,0.f,0.f,0.f};
#pragma unroll
            for (int kb = 0; kb < 4; kb++) {
                uint4 bf = *(const uint4*)&wp[((nt*4 + kb)*64 + lane)*4];
                acc = mfma16(afr[kb], bf, acc);
            }
            const int n  = nt*16 + n15;
            const int mb = mt*16 + (qd << 2);
#pragma unroll
            for (int r = 0; r < 4; r++) sXl3[(mb + r)*72 + n] = f2h(acc[r]);
            uint2 u;
            u.x = h2u(pk(acc[0], acc[1]));
            u.y = h2u(pk(acc[2], acc[3]));
            *(uint2*)&sXlB3[n*72 + mb] = u;
        }
    }
    // R projection (only this block's 16 nodes): waves 0-3, nt = w
    if (w < 4) {
        uint4 afq[4];
        load_afr_glb(gxRow, q, lane, afq);
        const u32* wp = wpk + 36864;
        f4 acc = {0.f,0.f,0.f,0.f};
#pragma unroll
        for (int kb = 0; kb < 4; kb++) {
            uint4 bf = *(const uint4*)&wp[((w*4 + kb)*64 + lane)*4];
            acc = mfma16(afq[kb], bf, acc);
        }
        const int n = w*16 + n15;
#pragma unroll
        for (int r = 0; r < 4; r++)
            sXrP3[((n >> 3)*16 + (qd << 2) + r)*8 + (n & 7)] = f2h(acc[r]);
    }
    __syncthreads();

    // Al3[i] (8-way c-split: 8 channels per wave)
    {
        h2 a2l[4];
#pragma unroll
        for (int qq = 0; qq < 4; qq++) a2l[qq] = pk(att3[w*8 + 2*qq], att3[w*8 + 2*qq + 1]);
        uint4 v = *(const uint4*)&sXl3[lane*72 + w*8];
        float al = 0.f;
        al = dot2(b2h(v.x), a2l[0], al);
        al = dot2(b2h(v.y), a2l[1], al);
        al = dot2(b2h(v.z), a2l[2], al);
        al = dot2(b2h(v.w), a2l[3], al);
        sPart[w*64 + lane] = al;
    }
    __syncthreads();
    if (t < 64) {
        sAl3[t] = ((sPart[t] + sPart[64+t]) + (sPart[128+t] + sPart[192+t]))
                + ((sPart[256+t] + sPart[320+t]) + (sPart[384+t] + sPart[448+t]));
    }
    __syncthreads();

    // scores3: thread (w, is, jj): 2 i's for dst j0+jj
    {
        const int jj = n15;
        const int is = qd;
        const int j  = j0 + jj;
        h2 a3[32], xr3[32];
#pragma unroll
        for (int qq = 0; qq < 32; qq++) a3[qq] = pk(att3[2*qq], att3[2*qq + 1]);
#pragma unroll
        for (int s = 0; s < 8; s++) {
            uint4 v = *(const uint4*)&sXrP3[(s*16 + jj)*8];
            xr3[s*4+0] = b2h(v.x); xr3[s*4+1] = b2h(v.y);
            xr3[s*4+2] = b2h(v.z); xr3[s*4+3] = b2h(v.w);
        }
        float Ar = 0.f;
#pragma unroll
        for (int qq = 0; qq < 32; qq++) Ar = dot2(a3[qq], xr3[qq], Ar);
        const float impj = sImp[j];
        const int i0 = w*8 + is*2;

        float p0, p1;
        {
            const int i = i0;
            const uint4* pl = (const uint4*)&sXl3[i*72];
            float S0 = 0.f, S1 = 0.f;
#pragma unroll
            for (int c4 = 0; c4 < 8; c4++) {
                uint4 v = pl[c4];
                S0 = dot2(a3[c4*4+0], abs2(b2h(v.x) + xr3[c4*4+0]), S0);
                S1 = dot2(a3[c4*4+1], abs2(b2h(v.y) + xr3[c4*4+1]), S1);
                S0 = dot2(a3[c4*4+2], abs2(b2h(v.z) + xr3[c4*4+2]), S0);
                S1 = dot2(a3[c4*4+3], abs2(b2h(v.w) + xr3[c4*4+3]), S1);
            }
            float e  = 0.6f*(sAl3[i] + Ar) + 0.4f*(S0 + S1);
            float ad = (i == j) ? 1.f : impj * sImp[i];
            p0 = (ad != 0.f) ? __expf(e) : 0.f;
        }
        {
            const int i = i0 + 1;
            const uint4* pl = (const uint4*)&sXl3[i*72];
            float S0 = 0.f, S1 = 0.f;
#pragma unroll
            for (int c4 = 0; c4 < 8; c4++) {
                uint4 v = pl[c4];
                S0 = dot2(a3[c4*4+0], abs2(b2h(v.x) + xr3[c4*4+0]), S0);
                S1 = dot2(a3[c4*4+1], abs2(b2h(v.y) + xr3[c4*4+1]), S1);
                S0 = dot2(a3[c4*4+2], abs2(b2h(v.z) + xr3[c4*4+2]), S0);
                S1 = dot2(a3[c4*4+3], abs2(b2h(v.w) + xr3[c4*4+3]), S1);
            }
            float e  = 0.6f*(sAl3[i] + Ar) + 0.4f*(S0 + S1);
            float ad = (i == j) ? 1.f : impj * sImp[i];
            p1 = (ad != 0.f) ? __expf(e) : 0.f;
        }
        h2 pp = pk(p0, p1);
        *(u32*)&sP3[jj*72 + i0] = h2u(pp);
        sPart[(w*4 + is)*16 + jj] = (float)pp[0] + (float)pp[1];
    }
    __syncthreads();
    if (t < 16) {
        float s = 0.f;
#pragma unroll
        for (int g = 0; g < 32; g++) s += sPart[g*16 + t];
        sRl[t] = 1.f / s;
    }

    // agg3 via MFMA: out[j,c] = sum_i P3[i,j]*xl3[i,c]; waves 0-3: cb = w (16-ch tile)
    f4 acc3 = {0.f,0.f,0.f,0.f};
    if (w < 4) {
#pragma unroll
        for (int ks = 0; ks < 2; ks++) {
            uint4 af = *(const uint4*)&sP3[n15*72 + ks*32 + (lane >> 4)*8];
            uint4 bf = *(const uint4*)&sXlB3[(w*16 + n15)*72 + ks*32 + (lane >> 4)*8];
            acc3 = mfma16(af, bf, acc3);
        }
    }
    __syncthreads();   // sRl ready
    if (w < 4) {
        const int c  = w*16 + n15;
        const float bc = b3[c];
#pragma unroll
        for (int r = 0; r < 4; r++) {
            const int jl = (lane >> 4)*4 + r;
            out[(size_t)b*4096 + (size_t)(j0 + jl)*64 + c] = fmaf(acc3[r], sRl[jl], bc);
        }
    }
}

extern "C" void kernel_launch(void* const* d_in, const int* in_sizes, int n_in,
                              void* d_out, int out_size, void* d_ws, size_t ws_size,
                              hipStream_t stream) {
    (void)in_sizes; (void)n_in; (void)ws_size; (void)out_size;
    const float* team_obs          = (const float*)d_in[0];
    const float* target_obs        = (const float*)d_in[1];
    const float* team_mask         = (const float*)d_in[2];
    const float* local_target_mask = (const float*)d_in[3];
    const float* W_emb             = (const float*)d_in[4];
    const float* b_emb             = (const float*)d_in[5];
    const float* Wl1               = (const float*)d_in[6];
    const float* Wr1               = (const float*)d_in[7];
    const float* att1              = (const float*)d_in[8];
    const float* b1                = (const float*)d_in[9];
    const float* Wl2               = (const float*)d_in[10];
    const float* Wr2               = (const float*)d_in[11];
    const float* att2              = (const float*)d_in[12];
    const float* b2                = (const float*)d_in[13];
    const float* Wl3               = (const float*)d_in[14];
    const float* Wr3               = (const float*)d_in[15];
    const float* att3              = (const float*)d_in[16];
    const float* b3                = (const float*)d_in[17];
    const float* ln1_g             = (const float*)d_in[18];
    const float* ln1_b             = (const float*)d_in[19];
    const float* ln2_g             = (const float*)d_in[20];
    const float* ln2_b             = (const float*)d_in[21];
    float* out = (float*)d_out;

    u32* wpk = (u32*)d_ws;                 // 163840 B packed weights
    u32* gx2 = (u32*)d_ws + 40960;         // 2 MB layer-2 activations
    u32* gx1 = (u32*)d_out;                // d_out reused as layer-1 activations (2 MB exact)

    pack_weights<<<dim3(160), dim3(256), 0, stream>>>(Wl1, Wr1, Wl2, Wr2, Wl3, Wr3, wpk);
    gnn_l1<<<dim3(512), dim3(512), 0, stream>>>(
        team_obs, target_obs, team_mask, local_target_mask, W_emb, b_emb,
        att1, b1, ln1_g, ln1_b, wpk, gx1);
    gnn_l2<<<dim3(512), dim3(512), 0, stream>>>(
        team_mask, local_target_mask, att2, b2, ln2_g, ln2_b, wpk, gx1, gx2);
    gnn_l3<<<dim3(512), dim3(512), 0, stream>>>(
        team_mask, local_target_mask, att3, b3, wpk, gx2, out);
}